// Round 9
// baseline (15801.671 us; speedup 1.0000x reference)
//
#include <hip/hip_runtime.h>
#include <stdint.h>

#define NB 256      // batch
#define TSEQ 1024   // sequence length
#define TT_MAX 64

typedef _Float16 f16;
typedef _Float16 h2 __attribute__((ext_vector_type(2)));

static __device__ __forceinline__ uint32_t pkh2(float a, float b) {
  h2 v; v[0] = (f16)a; v[1] = (f16)b;
  return __builtin_bit_cast(uint32_t, v);
}

#if __has_builtin(__builtin_amdgcn_fdot2)
static __device__ __forceinline__ float dot2u(uint32_t w, uint32_t h, float c) {
  return __builtin_amdgcn_fdot2(__builtin_bit_cast(h2, w), __builtin_bit_cast(h2, h), c, false);
}
#else
static __device__ __forceinline__ float dot2u(uint32_t w, uint32_t h, float c) {
  h2 a = __builtin_bit_cast(h2, w), b = __builtin_bit_cast(h2, h);
  return c + (float)a[0] * (float)b[0] + (float)a[1] * (float)b[1];
}
#endif

#if __has_builtin(__builtin_amdgcn_rcpf)
#define RCPF(x) __builtin_amdgcn_rcpf(x)
#else
#define RCPF(x) (1.0f / (x))
#endif

static __device__ __forceinline__ float sigm(float x) {
  return RCPF(1.0f + exp2f(-1.44269504f * x));
}
static __device__ __forceinline__ float tanh_f(float x) {
  return 1.0f - 2.0f * RCPF(1.0f + exp2f(2.88539008f * x));
}

// ---------------------------------------------------------------------------
// Precompute kernel (unchanged): gi_x'[t][b][768], zx'[t][b][64]
// ---------------------------------------------------------------------------
__global__ __launch_bounds__(256, 2) void vrnn_pre(
    const float* __restrict__ x, const float* __restrict__ W_ih,
    const float* __restrict__ b_ih, const float* __restrict__ b_hh,
    const float* __restrict__ emW, const float* __restrict__ emb,
    const float* __restrict__ esW, const float* __restrict__ esb,
    f16* __restrict__ gix, f16* __restrict__ zx,
    int chunk_t0, int TT, int nTT)
{
  const int tid = threadIdx.x;
  const int b  = blockIdx.x / nTT;
  const int tt = blockIdx.x % nTT;
  const int tloc0 = tt * TT;

  uint32_t wx[3][32];
  float bias[3];
  #pragma unroll
  for (int rr = 0; rr < 3; ++rr) {
    int j = tid + rr * 256;
    const float4* wr = (const float4*)(W_ih + (size_t)j * 96);
    #pragma unroll
    for (int p4 = 0; p4 < 16; ++p4) {
      float4 v = wr[p4];
      wx[rr][2 * p4]     = pkh2(v.x, v.y);
      wx[rr][2 * p4 + 1] = pkh2(v.z, v.w);
    }
    bias[rr] = b_ih[j] + (rr < 2 ? b_hh[j] : 0.0f);  // fold b_hh into r,z rows only
  }
  uint32_t we[32]; float ebias = 0.0f;
  if (tid < 64) {
    const float* src = (tid < 32) ? (emW + (size_t)tid * 320)
                                  : (esW + (size_t)(tid - 32) * 320);
    #pragma unroll
    for (int p = 0; p < 32; ++p) we[p] = pkh2(src[2 * p], src[2 * p + 1]);
    ebias = (tid < 32) ? emb[tid] : esb[tid - 32];
  }

  __shared__ uint32_t xs[TT_MAX * 32];
  for (int idx = tid; idx < TT * 32; idx += 256) {
    int tl = idx >> 5, pk = idx & 31;
    size_t base = ((size_t)b * TSEQ + (chunk_t0 + tloc0 + tl)) * 64 + 2 * pk;
    xs[idx] = pkh2(x[base], x[base + 1]);
  }
  __syncthreads();

  for (int tl = 0; tl < TT; ++tl) {
    float a0 = bias[0], a1 = bias[1], a2 = bias[2];
    #pragma unroll
    for (int p = 0; p < 32; ++p) {
      uint32_t u = xs[tl * 32 + p];
      a0 = dot2u(wx[0][p], u, a0);
      a1 = dot2u(wx[1][p], u, a1);
      a2 = dot2u(wx[2][p], u, a2);
    }
    size_t ob = (size_t)(tloc0 + tl) * NB + b;
    f16* g = gix + ob * 768;
    g[tid] = (f16)a0; g[tid + 256] = (f16)a1; g[tid + 512] = (f16)a2;
    if (tid < 64) {
      float a3 = ebias;
      #pragma unroll
      for (int p = 0; p < 32; ++p) a3 = dot2u(we[p], xs[tl * 32 + p], a3);
      zx[ob * 64 + tid] = (f16)a3;
    }
  }
}

// ---------------------------------------------------------------------------
// Recurrent kernel v3.1: 1024 threads (16 waves), one block per batch element.
// R8 post-mortem: amdgpu_waves_per_eu(4) sets only MIN; allocator targeted
// 8 waves/EU -> 64-VGPR budget -> the 96-reg wh array spilled (11.5 GB HBM,
// VALUBusy 8%). Pin the range with (4,4): budget = 512/4 = 128 >= demand
// ~119. LDS 87.5 KB already limits to 1 block/CU = 4 waves/EU, so the pin
// sacrifices nothing.
// ---------------------------------------------------------------------------
__global__ __attribute__((amdgpu_flat_work_group_size(1024, 1024), amdgpu_waves_per_eu(4, 4)))
void vrnn_rec(
    const f16* __restrict__ gix, const f16* __restrict__ zx,
    const float* __restrict__ eps,
    const float* __restrict__ W_hh, const float* __restrict__ W_ih,
    const float* __restrict__ emW, const float* __restrict__ esW,
    const float* __restrict__ b_hh,
    float* __restrict__ hws, float* __restrict__ out,
    int t0, int Tlen, int first, int last)
{
  const int tid  = threadIdx.x;
  const int b    = blockIdx.x;
  const int hrow = tid >> 2;      // 0..255 : hidden index / gate-row base
  const int q    = tid & 3;       // k-quarter (interleaved uint4 blocks)

  // ---- W_hh quarter rows in registers: 3 x 32 packed f16 pairs = 96 VGPRs ----
  // Quarter q owns uint4 blocks j = q + 4*p4 (p4=0..7), i.e. f16 k in [8j,8j+8).
  uint32_t wh[3][32];
  #pragma unroll
  for (int rr = 0; rr < 3; ++rr) {
    const float* rowp = W_hh + (size_t)(hrow + rr * 256) * 256;
    #pragma unroll
    for (int p4 = 0; p4 < 8; ++p4) {
      int j = q + 4 * p4;
      const float4* wp = (const float4*)(rowp + 8 * j);
      float4 v0 = wp[0], v1 = wp[1];
      wh[rr][4 * p4]     = pkh2(v0.x, v0.y);
      wh[rr][4 * p4 + 1] = pkh2(v0.z, v0.w);
      wh[rr][4 * p4 + 2] = pkh2(v1.x, v1.y);
      wh[rr][4 * p4 + 3] = pkh2(v1.z, v1.w);
    }
  }
  const float bhn = b_hh[512 + hrow];   // n-gate hidden bias (inside r*(h_n+b))

  // ---- LDS ----
  __shared__ uint32_t wzl[768 * 16];     // 48 KB, z-part of W_ih, XOR-swizzled
  __shared__ uint32_t encw[64 * 128];    // 32 KB, enc h-part, rotation-swizzled
  __shared__ __align__(16) f16 hf[2][256];
  __shared__ float encp[1024];
  __shared__ uint32_t zu[16];

  for (int idx = tid; idx < 768 * 16; idx += 1024) {
    int j = idx >> 4, pz = idx & 15;
    wzl[j * 16 + (pz ^ (j & 15))] = pkh2(W_ih[(size_t)j * 96 + 64 + 2 * pz],
                                         W_ih[(size_t)j * 96 + 64 + 2 * pz + 1]);
  }
  for (int idx = tid; idx < 64 * 128; idx += 1024) {
    int row = idx >> 7, pc = idx & 127;
    const float* src = (row < 32) ? (emW + (size_t)row * 320 + 64)
                                  : (esW + (size_t)(row - 32) * 320 + 64);
    encw[(row << 7) + ((pc + row) & 127)] = pkh2(src[2 * pc], src[2 * pc + 1]);
  }

  float hm = 0.0f;
  if (q == 0) {
    hm = first ? 0.0f : hws[b * 256 + hrow];
    hf[0][hrow] = (f16)hm;
  }
  __syncthreads();

  // ---- stream prefetch for t=0 ----
  float pf_g0 = 0.0f, pf_g1 = 0.0f, pf_g2 = 0.0f;
  if (q == 0) {
    const f16* gp0 = gix + (size_t)b * 768;
    pf_g0 = (float)gp0[hrow]; pf_g1 = (float)gp0[hrow + 256]; pf_g2 = (float)gp0[hrow + 512];
  }
  float pf_zm = 0.0f, pf_zl = 0.0f, pf_ep = 0.0f;
  if (tid < 32) {
    const f16* zp = zx + (size_t)b * 64;
    pf_zm = (float)zp[tid]; pf_zl = (float)zp[32 + tid];
    pf_ep = eps[((size_t)t0 * NB + b) * 32 + tid];
  }

  const int erow = tid & 63, eq = tid >> 6;      // enc partials: 16 groups x 8 k-pairs
  const uint32_t* encw_r = encw + (erow << 7);
  const int zswz = hrow & 15;

  for (int tl = 0; tl < Tlen; ++tl) {
    const int cur = tl & 1, nxt = cur ^ 1;
    const uint32_t* hu = (const uint32_t*)&hf[cur][0];

    // ---- phase A: encoder h-part partials (8 k-pairs per thread) ----
    float epacc = 0.0f;
    #pragma unroll
    for (int p = 0; p < 8; ++p) {
      int pc = eq * 8 + p;
      epacc = dot2u(encw_r[(pc + erow) & 127], hu[pc], epacc);
    }
    encp[tid] = epacc;
    __syncthreads();  // b1

    // ---- phase B: z (32 threads) || gh (all threads) ----
    if (tid < 32) {
      float mu = pf_zm, lv = pf_zl;
      #pragma unroll
      for (int qq = 0; qq < 16; ++qq) {
        mu += encp[qq * 64 + tid];
        lv += encp[qq * 64 + 32 + tid];
      }
      float z = mu + pf_ep * exp2f(0.72134752f * lv);   // mu + eps*exp(0.5*lv)
      ((f16*)zu)[tid] = (f16)z;
    }
    // gh: 8 x ds_read_b128 (bank-disjoint across quarters) + 96 dot2
    const uint4* hu4 = (const uint4*)hu;
    float g0 = 0.0f, g1 = 0.0f, g2 = 0.0f;
    #pragma unroll
    for (int p4 = 0; p4 < 8; ++p4) {
      uint4 u4 = hu4[q + 4 * p4];
      g0 = dot2u(wh[0][4 * p4],     u4.x, g0);
      g1 = dot2u(wh[1][4 * p4],     u4.x, g1);
      g2 = dot2u(wh[2][4 * p4],     u4.x, g2);
      g0 = dot2u(wh[0][4 * p4 + 1], u4.y, g0);
      g1 = dot2u(wh[1][4 * p4 + 1], u4.y, g1);
      g2 = dot2u(wh[2][4 * p4 + 1], u4.y, g2);
      g0 = dot2u(wh[0][4 * p4 + 2], u4.z, g0);
      g1 = dot2u(wh[1][4 * p4 + 2], u4.z, g1);
      g2 = dot2u(wh[2][4 * p4 + 2], u4.z, g2);
      g0 = dot2u(wh[0][4 * p4 + 3], u4.w, g0);
      g1 = dot2u(wh[1][4 * p4 + 3], u4.w, g1);
      g2 = dot2u(wh[2][4 * p4 + 3], u4.w, g2);
    }
    __syncthreads();  // b2  (z visible)

    // ---- phase C: gi_z (4 packed k per quarter), 4-lane reduce, gates ----
    float q0 = 0.0f, q1 = 0.0f, q2 = 0.0f;
    #pragma unroll
    for (int p = 0; p < 4; ++p) {
      int pz = q * 4 + p;
      int swz = pz ^ zswz;
      uint32_t u = zu[pz];
      q0 = dot2u(wzl[(hrow)       * 16 + swz], u, q0);
      q1 = dot2u(wzl[(hrow + 256) * 16 + swz], u, q1);
      q2 = dot2u(wzl[(hrow + 512) * 16 + swz], u, q2);
    }
    // r,u gates: fold z-part in (sigmoid of total sum). n gate: keep the
    // z-part separate (it must NOT be scaled by r).
    g0 += q0; g1 += q1; g2 += q2;
    g0 += __shfl_xor(g0, 1); g0 += __shfl_xor(g0, 2);
    g1 += __shfl_xor(g1, 1); g1 += __shfl_xor(g1, 2);
    g2 += __shfl_xor(g2, 1); g2 += __shfl_xor(g2, 2);
    float z_n = q2 + __shfl_xor(q2, 1);
    z_n += __shfl_xor(z_n, 2);       // full z-part of n row
    float n_h = g2 - z_n;            // pure W_hh_n @ h

    if (q == 0) {
      float r  = sigm(pf_g0 + g0);
      float uu = sigm(pf_g1 + g1);
      float n  = tanh_f(pf_g2 + z_n + r * (n_h + bhn));
      hm = (1.0f - uu) * n + uu * hm;
      hf[nxt][hrow] = (f16)hm;
    }

    // ---- prefetch streams for tl+1 ----
    int tn = (tl + 1 < Tlen) ? tl + 1 : tl;
    if (q == 0) {
      const f16* gp = gix + ((size_t)tn * NB + b) * 768;
      pf_g0 = (float)gp[hrow]; pf_g1 = (float)gp[hrow + 256]; pf_g2 = (float)gp[hrow + 512];
    }
    if (tid < 32) {
      const f16* zp = zx + ((size_t)tn * NB + b) * 64;
      pf_zm = (float)zp[tid]; pf_zl = (float)zp[32 + tid];
      pf_ep = eps[((size_t)(t0 + tn) * NB + b) * 32 + tid];
    }
    __syncthreads();  // b3  (h_new visible, streams in flight)
  }

  if (q == 0) {
    if (last) out[b * 256 + hrow] = hm;
    else      hws[b * 256 + hrow] = hm;
  }
}

extern "C" void kernel_launch(void* const* d_in, const int* in_sizes, int n_in,
                              void* d_out, int out_size, void* d_ws, size_t ws_size,
                              hipStream_t stream) {
  const float* x    = (const float*)d_in[0];
  const float* eps  = (const float*)d_in[1];
  const float* emW  = (const float*)d_in[2];
  const float* emb  = (const float*)d_in[3];
  const float* esW  = (const float*)d_in[4];
  const float* esb  = (const float*)d_in[5];
  const float* W_ih = (const float*)d_in[10];
  const float* W_hh = (const float*)d_in[11];
  const float* b_ih = (const float*)d_in[12];
  const float* b_hh = (const float*)d_in[13];
  float* out = (float*)d_out;

  const size_t hbytes = (size_t)NB * 256 * 4;
  int Tc = TSEQ;
  while (Tc > 8 && hbytes + (size_t)Tc * NB * (768 + 64) * 2 > ws_size) Tc >>= 1;

  float* hws = (float*)d_ws;
  f16* gix = (f16*)((char*)d_ws + hbytes);
  f16* zx  = gix + (size_t)Tc * NB * 768;

  int nch = TSEQ / Tc;
  int TT  = Tc < 64 ? Tc : 64;
  int nTT = Tc / TT;

  for (int c = 0; c < nch; ++c) {
    vrnn_pre<<<dim3(NB * nTT), dim3(256), 0, stream>>>(
        x, W_ih, b_ih, b_hh, emW, emb, esW, esb, gix, zx, c * Tc, TT, nTT);
    vrnn_rec<<<dim3(NB), dim3(1024), 0, stream>>>(
        gix, zx, eps, W_hh, W_ih, emW, esW, b_hh, hws, out,
        c * Tc, Tc, c == 0 ? 1 : 0, c == nch - 1 ? 1 : 0);
  }
}

// Round 10
// 15622.073 us; speedup vs baseline: 1.0115x; 1.0115x over previous
//
#include <hip/hip_runtime.h>
#include <stdint.h>

#define NB 256      // batch
#define TSEQ 1024   // sequence length
#define TT_MAX 64

typedef _Float16 f16;
typedef _Float16 h2 __attribute__((ext_vector_type(2)));

static __device__ __forceinline__ uint32_t pkh2(float a, float b) {
  h2 v; v[0] = (f16)a; v[1] = (f16)b;
  return __builtin_bit_cast(uint32_t, v);
}

#if __has_builtin(__builtin_amdgcn_fdot2)
static __device__ __forceinline__ float dot2u(uint32_t w, uint32_t h, float c) {
  return __builtin_amdgcn_fdot2(__builtin_bit_cast(h2, w), __builtin_bit_cast(h2, h), c, false);
}
#else
static __device__ __forceinline__ float dot2u(uint32_t w, uint32_t h, float c) {
  h2 a = __builtin_bit_cast(h2, w), b = __builtin_bit_cast(h2, h);
  return c + (float)a[0] * (float)b[0] + (float)a[1] * (float)b[1];
}
#endif

#if __has_builtin(__builtin_amdgcn_rcpf)
#define RCPF(x) __builtin_amdgcn_rcpf(x)
#else
#define RCPF(x) (1.0f / (x))
#endif

static __device__ __forceinline__ float sigm(float x) {
  return RCPF(1.0f + exp2f(-1.44269504f * x));
}
static __device__ __forceinline__ float tanh_f(float x) {
  return 1.0f - 2.0f * RCPF(1.0f + exp2f(2.88539008f * x));
}

// ---------------------------------------------------------------------------
// Precompute kernel (unchanged): gi_x'[t][b][768], zx'[t][b][64]
// (256,2) = 2 blocks/CU -> 2 waves/SIMD -> 256-VGPR budget: holds its ~140
// live regs spill-free, consistent with the min-BLOCKS launch_bounds model.
// ---------------------------------------------------------------------------
__global__ __launch_bounds__(256, 2) void vrnn_pre(
    const float* __restrict__ x, const float* __restrict__ W_ih,
    const float* __restrict__ b_ih, const float* __restrict__ b_hh,
    const float* __restrict__ emW, const float* __restrict__ emb,
    const float* __restrict__ esW, const float* __restrict__ esb,
    f16* __restrict__ gix, f16* __restrict__ zx,
    int chunk_t0, int TT, int nTT)
{
  const int tid = threadIdx.x;
  const int b  = blockIdx.x / nTT;
  const int tt = blockIdx.x % nTT;
  const int tloc0 = tt * TT;

  uint32_t wx[3][32];
  float bias[3];
  #pragma unroll
  for (int rr = 0; rr < 3; ++rr) {
    int j = tid + rr * 256;
    const float4* wr = (const float4*)(W_ih + (size_t)j * 96);
    #pragma unroll
    for (int p4 = 0; p4 < 16; ++p4) {
      float4 v = wr[p4];
      wx[rr][2 * p4]     = pkh2(v.x, v.y);
      wx[rr][2 * p4 + 1] = pkh2(v.z, v.w);
    }
    bias[rr] = b_ih[j] + (rr < 2 ? b_hh[j] : 0.0f);  // fold b_hh into r,z rows only
  }
  uint32_t we[32]; float ebias = 0.0f;
  if (tid < 64) {
    const float* src = (tid < 32) ? (emW + (size_t)tid * 320)
                                  : (esW + (size_t)(tid - 32) * 320);
    #pragma unroll
    for (int p = 0; p < 32; ++p) we[p] = pkh2(src[2 * p], src[2 * p + 1]);
    ebias = (tid < 32) ? emb[tid] : esb[tid - 32];
  }

  __shared__ uint32_t xs[TT_MAX * 32];
  for (int idx = tid; idx < TT * 32; idx += 256) {
    int tl = idx >> 5, pk = idx & 31;
    size_t base = ((size_t)b * TSEQ + (chunk_t0 + tloc0 + tl)) * 64 + 2 * pk;
    xs[idx] = pkh2(x[base], x[base + 1]);
  }
  __syncthreads();

  for (int tl = 0; tl < TT; ++tl) {
    float a0 = bias[0], a1 = bias[1], a2 = bias[2];
    #pragma unroll
    for (int p = 0; p < 32; ++p) {
      uint32_t u = xs[tl * 32 + p];
      a0 = dot2u(wx[0][p], u, a0);
      a1 = dot2u(wx[1][p], u, a1);
      a2 = dot2u(wx[2][p], u, a2);
    }
    size_t ob = (size_t)(tloc0 + tl) * NB + b;
    f16* g = gix + ob * 768;
    g[tid] = (f16)a0; g[tid + 256] = (f16)a1; g[tid + 512] = (f16)a2;
    if (tid < 64) {
      float a3 = ebias;
      #pragma unroll
      for (int p = 0; p < 32; ++p) a3 = dot2u(we[p], xs[tl * 32 + p], a3);
      zx[ob * 64 + tid] = (f16)a3;
    }
  }
}

// ---------------------------------------------------------------------------
// Recurrent kernel v3.2: 1024 threads (16 waves), one block per batch element.
// R1/R6/R8/R9 post-mortem: hipcc's launch_bounds 2nd arg behaves as min
// BLOCKS per CU (default 2). 1024-thread block at 2 blocks/CU -> 8 waves/SIMD
// -> 64-VGPR budget -> the 96-reg wh array spilled (11.5 GB HBM, VALUBusy 8%).
// Fix: __launch_bounds__(1024, 1): 1 block/CU -> 4 waves/SIMD -> 128-VGPR
// budget >= ~119 demand. LDS 87.5 KB forbids 2 blocks/CU anyway, so min=1
// costs nothing. Prologue is chunked with sched_barrier(0) so the weight-load
// staging cannot push estimated pressure over 128 (which triggers wholesale
// spill, per R9).
// ---------------------------------------------------------------------------
__global__ __launch_bounds__(1024, 1) void vrnn_rec(
    const f16* __restrict__ gix, const f16* __restrict__ zx,
    const float* __restrict__ eps,
    const float* __restrict__ W_hh, const float* __restrict__ W_ih,
    const float* __restrict__ emW, const float* __restrict__ esW,
    const float* __restrict__ b_hh,
    float* __restrict__ hws, float* __restrict__ out,
    int t0, int Tlen, int first, int last)
{
  const int tid  = threadIdx.x;
  const int b    = blockIdx.x;
  const int hrow = tid >> 2;      // 0..255 : hidden index / gate-row base
  const int q    = tid & 3;       // k-quarter (interleaved uint4 blocks)

  // ---- W_hh quarter rows in registers: 3 x 32 packed f16 pairs = 96 VGPRs ----
  // Quarter q owns uint4 blocks j = q + 4*p4 (p4=0..7), i.e. f16 k in [8j,8j+8).
  // Loaded in 3 row-chunks separated by sched_barrier(0) to cap staging pressure.
  uint32_t wh[3][32];
  #pragma unroll
  for (int rr = 0; rr < 3; ++rr) {
    const float* rowp = W_hh + (size_t)(hrow + rr * 256) * 256;
    #pragma unroll
    for (int p4 = 0; p4 < 8; ++p4) {
      int j = q + 4 * p4;
      const float4* wp = (const float4*)(rowp + 8 * j);
      float4 v0 = wp[0], v1 = wp[1];
      wh[rr][4 * p4]     = pkh2(v0.x, v0.y);
      wh[rr][4 * p4 + 1] = pkh2(v0.z, v0.w);
      wh[rr][4 * p4 + 2] = pkh2(v1.x, v1.y);
      wh[rr][4 * p4 + 3] = pkh2(v1.z, v1.w);
    }
    __builtin_amdgcn_sched_barrier(0);   // keep load-stage pressure chunked
  }
  const float bhn = b_hh[512 + hrow];   // n-gate hidden bias (inside r*(h_n+b))

  // ---- LDS ----
  __shared__ uint32_t wzl[768 * 16];     // 48 KB, z-part of W_ih, XOR-swizzled
  __shared__ uint32_t encw[64 * 128];    // 32 KB, enc h-part, rotation-swizzled
  __shared__ __align__(16) f16 hf[2][256];
  __shared__ float encp[1024];
  __shared__ uint32_t zu[16];

  for (int idx = tid; idx < 768 * 16; idx += 1024) {
    int j = idx >> 4, pz = idx & 15;
    wzl[j * 16 + (pz ^ (j & 15))] = pkh2(W_ih[(size_t)j * 96 + 64 + 2 * pz],
                                         W_ih[(size_t)j * 96 + 64 + 2 * pz + 1]);
  }
  for (int idx = tid; idx < 64 * 128; idx += 1024) {
    int row = idx >> 7, pc = idx & 127;
    const float* src = (row < 32) ? (emW + (size_t)row * 320 + 64)
                                  : (esW + (size_t)(row - 32) * 320 + 64);
    encw[(row << 7) + ((pc + row) & 127)] = pkh2(src[2 * pc], src[2 * pc + 1]);
  }

  float hm = 0.0f;
  if (q == 0) {
    hm = first ? 0.0f : hws[b * 256 + hrow];
    hf[0][hrow] = (f16)hm;
  }
  __syncthreads();

  // ---- stream prefetch for t=0 ----
  float pf_g0 = 0.0f, pf_g1 = 0.0f, pf_g2 = 0.0f;
  if (q == 0) {
    const f16* gp0 = gix + (size_t)b * 768;
    pf_g0 = (float)gp0[hrow]; pf_g1 = (float)gp0[hrow + 256]; pf_g2 = (float)gp0[hrow + 512];
  }
  float pf_zm = 0.0f, pf_zl = 0.0f, pf_ep = 0.0f;
  if (tid < 32) {
    const f16* zp = zx + (size_t)b * 64;
    pf_zm = (float)zp[tid]; pf_zl = (float)zp[32 + tid];
    pf_ep = eps[((size_t)t0 * NB + b) * 32 + tid];
  }

  const int erow = tid & 63, eq = tid >> 6;      // enc partials: 16 groups x 8 k-pairs
  const uint32_t* encw_r = encw + (erow << 7);
  const int zswz = hrow & 15;

  for (int tl = 0; tl < Tlen; ++tl) {
    const int cur = tl & 1, nxt = cur ^ 1;
    const uint32_t* hu = (const uint32_t*)&hf[cur][0];

    // ---- phase A: encoder h-part partials (8 k-pairs per thread) ----
    float epacc = 0.0f;
    #pragma unroll
    for (int p = 0; p < 8; ++p) {
      int pc = eq * 8 + p;
      epacc = dot2u(encw_r[(pc + erow) & 127], hu[pc], epacc);
    }
    encp[tid] = epacc;
    __syncthreads();  // b1

    // ---- phase B: z (32 threads) || gh (all threads) ----
    if (tid < 32) {
      float mu = pf_zm, lv = pf_zl;
      #pragma unroll
      for (int qq = 0; qq < 16; ++qq) {
        mu += encp[qq * 64 + tid];
        lv += encp[qq * 64 + 32 + tid];
      }
      float z = mu + pf_ep * exp2f(0.72134752f * lv);   // mu + eps*exp(0.5*lv)
      ((f16*)zu)[tid] = (f16)z;
    }
    // gh: 8 x ds_read_b128 (bank-disjoint across quarters) + 96 dot2
    const uint4* hu4 = (const uint4*)hu;
    float g0 = 0.0f, g1 = 0.0f, g2 = 0.0f;
    #pragma unroll
    for (int p4 = 0; p4 < 8; ++p4) {
      uint4 u4 = hu4[q + 4 * p4];
      g0 = dot2u(wh[0][4 * p4],     u4.x, g0);
      g1 = dot2u(wh[1][4 * p4],     u4.x, g1);
      g2 = dot2u(wh[2][4 * p4],     u4.x, g2);
      g0 = dot2u(wh[0][4 * p4 + 1], u4.y, g0);
      g1 = dot2u(wh[1][4 * p4 + 1], u4.y, g1);
      g2 = dot2u(wh[2][4 * p4 + 1], u4.y, g2);
      g0 = dot2u(wh[0][4 * p4 + 2], u4.z, g0);
      g1 = dot2u(wh[1][4 * p4 + 2], u4.z, g1);
      g2 = dot2u(wh[2][4 * p4 + 2], u4.z, g2);
      g0 = dot2u(wh[0][4 * p4 + 3], u4.w, g0);
      g1 = dot2u(wh[1][4 * p4 + 3], u4.w, g1);
      g2 = dot2u(wh[2][4 * p4 + 3], u4.w, g2);
    }
    __syncthreads();  // b2  (z visible)

    // ---- phase C: gi_z (4 packed k per quarter), 4-lane reduce, gates ----
    float q0 = 0.0f, q1 = 0.0f, q2 = 0.0f;
    #pragma unroll
    for (int p = 0; p < 4; ++p) {
      int pz = q * 4 + p;
      int swz = pz ^ zswz;
      uint32_t u = zu[pz];
      q0 = dot2u(wzl[(hrow)       * 16 + swz], u, q0);
      q1 = dot2u(wzl[(hrow + 256) * 16 + swz], u, q1);
      q2 = dot2u(wzl[(hrow + 512) * 16 + swz], u, q2);
    }
    // r,u gates: fold z-part in (sigmoid of total sum). n gate: keep the
    // z-part separate (it must NOT be scaled by r).
    g0 += q0; g1 += q1; g2 += q2;
    g0 += __shfl_xor(g0, 1); g0 += __shfl_xor(g0, 2);
    g1 += __shfl_xor(g1, 1); g1 += __shfl_xor(g1, 2);
    g2 += __shfl_xor(g2, 1); g2 += __shfl_xor(g2, 2);
    float z_n = q2 + __shfl_xor(q2, 1);
    z_n += __shfl_xor(z_n, 2);       // full z-part of n row
    float n_h = g2 - z_n;            // pure W_hh_n @ h

    if (q == 0) {
      float r  = sigm(pf_g0 + g0);
      float uu = sigm(pf_g1 + g1);
      float n  = tanh_f(pf_g2 + z_n + r * (n_h + bhn));
      hm = (1.0f - uu) * n + uu * hm;
      hf[nxt][hrow] = (f16)hm;
    }

    // ---- prefetch streams for tl+1 ----
    int tn = (tl + 1 < Tlen) ? tl + 1 : tl;
    if (q == 0) {
      const f16* gp = gix + ((size_t)tn * NB + b) * 768;
      pf_g0 = (float)gp[hrow]; pf_g1 = (float)gp[hrow + 256]; pf_g2 = (float)gp[hrow + 512];
    }
    if (tid < 32) {
      const f16* zp = zx + ((size_t)tn * NB + b) * 64;
      pf_zm = (float)zp[tid]; pf_zl = (float)zp[32 + tid];
      pf_ep = eps[((size_t)(t0 + tn) * NB + b) * 32 + tid];
    }
    __syncthreads();  // b3  (h_new visible, streams in flight)
  }

  if (q == 0) {
    if (last) out[b * 256 + hrow] = hm;
    else      hws[b * 256 + hrow] = hm;
  }
}

extern "C" void kernel_launch(void* const* d_in, const int* in_sizes, int n_in,
                              void* d_out, int out_size, void* d_ws, size_t ws_size,
                              hipStream_t stream) {
  const float* x    = (const float*)d_in[0];
  const float* eps  = (const float*)d_in[1];
  const float* emW  = (const float*)d_in[2];
  const float* emb  = (const float*)d_in[3];
  const float* esW  = (const float*)d_in[4];
  const float* esb  = (const float*)d_in[5];
  const float* W_ih = (const float*)d_in[10];
  const float* W_hh = (const float*)d_in[11];
  const float* b_ih = (const float*)d_in[12];
  const float* b_hh = (const float*)d_in[13];
  float* out = (float*)d_out;

  const size_t hbytes = (size_t)NB * 256 * 4;
  int Tc = TSEQ;
  while (Tc > 8 && hbytes + (size_t)Tc * NB * (768 + 64) * 2 > ws_size) Tc >>= 1;

  float* hws = (float*)d_ws;
  f16* gix = (f16*)((char*)d_ws + hbytes);
  f16* zx  = gix + (size_t)Tc * NB * 768;

  int nch = TSEQ / Tc;
  int TT  = Tc < 64 ? Tc : 64;
  int nTT = Tc / TT;

  for (int c = 0; c < nch; ++c) {
    vrnn_pre<<<dim3(NB * nTT), dim3(256), 0, stream>>>(
        x, W_ih, b_ih, b_hh, emW, emb, esW, esb, gix, zx, c * Tc, TT, nTT);
    vrnn_rec<<<dim3(NB), dim3(1024), 0, stream>>>(
        gix, zx, eps, W_hh, W_ih, emW, esW, b_hh, hws, out,
        c * Tc, Tc, c == 0 ? 1 : 0, c == nch - 1 ? 1 : 0);
  }
}

// Round 11
// 13693.509 us; speedup vs baseline: 1.1540x; 1.1408x over previous
//
#include <hip/hip_runtime.h>
#include <stdint.h>

#define NB 256      // batch
#define TSEQ 1024   // sequence length
#define TT_MAX 64

typedef _Float16 f16;
typedef _Float16 h2 __attribute__((ext_vector_type(2)));

static __device__ __forceinline__ uint32_t pkh2(float a, float b) {
  h2 v; v[0] = (f16)a; v[1] = (f16)b;
  return __builtin_bit_cast(uint32_t, v);
}

#if __has_builtin(__builtin_amdgcn_fdot2)
static __device__ __forceinline__ float dot2u(uint32_t w, uint32_t h, float c) {
  return __builtin_amdgcn_fdot2(__builtin_bit_cast(h2, w), __builtin_bit_cast(h2, h), c, false);
}
#else
static __device__ __forceinline__ float dot2u(uint32_t w, uint32_t h, float c) {
  h2 a = __builtin_bit_cast(h2, w), b = __builtin_bit_cast(h2, h);
  return c + (float)a[0] * (float)b[0] + (float)a[1] * (float)b[1];
}
#endif

#if __has_builtin(__builtin_amdgcn_rcpf)
#define RCPF(x) __builtin_amdgcn_rcpf(x)
#else
#define RCPF(x) (1.0f / (x))
#endif

static __device__ __forceinline__ float sigm(float x) {
  return RCPF(1.0f + exp2f(-1.44269504f * x));
}
static __device__ __forceinline__ float tanh_f(float x) {
  return 1.0f - 2.0f * RCPF(1.0f + exp2f(2.88539008f * x));
}

// ---------------------------------------------------------------------------
// One-time W_hh f16 prepack into thread-order: chunk c (= rr*8+p4), thread t
// owns rows (t>>2 + rr*256), K-quarter q=t&3, uint4 at whpk[(c*1024+t)*4].
// Coalesced dwordx4 both ways; ~0.4 MB written once.
// ---------------------------------------------------------------------------
__global__ __launch_bounds__(1024, 1) void vrnn_pack(
    const float* __restrict__ W_hh, uint32_t* __restrict__ whpk)
{
  const int t = threadIdx.x, c = blockIdx.x;
  const int rr = c >> 3, p4 = c & 7;
  const int hrow = t >> 2, q = t & 3;
  const int j = q + 4 * p4;
  const float* rowp = W_hh + (size_t)(hrow + rr * 256) * 256 + 8 * j;
  uint32_t o[4];
  o[0] = pkh2(rowp[0], rowp[1]);
  o[1] = pkh2(rowp[2], rowp[3]);
  o[2] = pkh2(rowp[4], rowp[5]);
  o[3] = pkh2(rowp[6], rowp[7]);
  *(uint4*)(whpk + ((size_t)c * 1024 + t) * 4) = *(const uint4*)o;
}

// ---------------------------------------------------------------------------
// Precompute kernel (unchanged): gi_x'[t][b][768], zx'[t][b][64]
// ---------------------------------------------------------------------------
__global__ __launch_bounds__(256, 2) void vrnn_pre(
    const float* __restrict__ x, const float* __restrict__ W_ih,
    const float* __restrict__ b_ih, const float* __restrict__ b_hh,
    const float* __restrict__ emW, const float* __restrict__ emb,
    const float* __restrict__ esW, const float* __restrict__ esb,
    f16* __restrict__ gix, f16* __restrict__ zx,
    int chunk_t0, int TT, int nTT)
{
  const int tid = threadIdx.x;
  const int b  = blockIdx.x / nTT;
  const int tt = blockIdx.x % nTT;
  const int tloc0 = tt * TT;

  uint32_t wx[3][32];
  float bias[3];
  #pragma unroll
  for (int rr = 0; rr < 3; ++rr) {
    int j = tid + rr * 256;
    const float4* wr = (const float4*)(W_ih + (size_t)j * 96);
    #pragma unroll
    for (int p4 = 0; p4 < 16; ++p4) {
      float4 v = wr[p4];
      wx[rr][2 * p4]     = pkh2(v.x, v.y);
      wx[rr][2 * p4 + 1] = pkh2(v.z, v.w);
    }
    bias[rr] = b_ih[j] + (rr < 2 ? b_hh[j] : 0.0f);  // fold b_hh into r,z rows only
  }
  uint32_t we[32]; float ebias = 0.0f;
  if (tid < 64) {
    const float* src = (tid < 32) ? (emW + (size_t)tid * 320)
                                  : (esW + (size_t)(tid - 32) * 320);
    #pragma unroll
    for (int p = 0; p < 32; ++p) we[p] = pkh2(src[2 * p], src[2 * p + 1]);
    ebias = (tid < 32) ? emb[tid] : esb[tid - 32];
  }

  __shared__ uint32_t xs[TT_MAX * 32];
  for (int idx = tid; idx < TT * 32; idx += 256) {
    int tl = idx >> 5, pk = idx & 31;
    size_t base = ((size_t)b * TSEQ + (chunk_t0 + tloc0 + tl)) * 64 + 2 * pk;
    xs[idx] = pkh2(x[base], x[base + 1]);
  }
  __syncthreads();

  for (int tl = 0; tl < TT; ++tl) {
    float a0 = bias[0], a1 = bias[1], a2 = bias[2];
    #pragma unroll
    for (int p = 0; p < 32; ++p) {
      uint32_t u = xs[tl * 32 + p];
      a0 = dot2u(wx[0][p], u, a0);
      a1 = dot2u(wx[1][p], u, a1);
      a2 = dot2u(wx[2][p], u, a2);
    }
    size_t ob = (size_t)(tloc0 + tl) * NB + b;
    f16* g = gix + ob * 768;
    g[tid] = (f16)a0; g[tid + 256] = (f16)a1; g[tid + 512] = (f16)a2;
    if (tid < 64) {
      float a3 = ebias;
      #pragma unroll
      for (int p = 0; p < 32; ++p) a3 = dot2u(we[p], xs[tl * 32 + p], a3);
      zx[ob * 64 + tid] = (f16)a3;
    }
  }
}

// ---------------------------------------------------------------------------
// Recurrent kernel v4: 1024 threads, one block per batch element.
// R8-R10 post-mortem: VGPR_Count=64 with WRITE_SIZE ~1MB => the compiler was
// REMATERIALIZING the loop-invariant weight loads (legal: const __restrict__),
// re-streaming all of W_hh as f32 from L2 every step — not scratch-spilling.
// Fix: (a) weights pre-packed to f16 once (vrnn_pack), loaded as 24 coalesced
// dwordx4; (b) each value pinned with asm volatile("":"+v") — an opaque asm
// result cannot be rematerialized, so the allocator must either keep it in a
// VGPR (the win) or truly spill to scratch (diagnosable via WRITE_SIZE).
// ---------------------------------------------------------------------------
__global__ __launch_bounds__(1024, 1) void vrnn_rec(
    const f16* __restrict__ gix, const f16* __restrict__ zx,
    const float* __restrict__ eps,
    const uint32_t* __restrict__ whpk, const float* __restrict__ W_ih,
    const float* __restrict__ emW, const float* __restrict__ esW,
    const float* __restrict__ b_hh,
    float* __restrict__ hws, float* __restrict__ out,
    int t0, int Tlen, int first, int last)
{
  const int tid  = threadIdx.x;
  const int b    = blockIdx.x;
  const int hrow = tid >> 2;      // 0..255 : hidden index / gate-row base
  const int q    = tid & 3;       // k-quarter (interleaved uint4 blocks)

  // ---- W_hh quarter rows: 96 packed f16 pairs, register-pinned ----
  uint32_t wh[3][32];
  {
    const uint4* wp = (const uint4*)whpk;
    #pragma unroll
    for (int c = 0; c < 24; ++c) {
      uint4 v = wp[c * 1024 + tid];
      wh[c >> 3][(c & 7) * 4 + 0] = v.x;
      wh[c >> 3][(c & 7) * 4 + 1] = v.y;
      wh[c >> 3][(c & 7) * 4 + 2] = v.z;
      wh[c >> 3][(c & 7) * 4 + 3] = v.w;
    }
  }
  #pragma unroll
  for (int rr = 0; rr < 3; ++rr) {
    #pragma unroll
    for (int i = 0; i < 32; ++i) {
      asm volatile("" : "+v"(wh[rr][i]));   // non-rematerializable register pin
    }
  }
  const float bhn = b_hh[512 + hrow];   // n-gate hidden bias (inside r*(h_n+b))

  // ---- LDS ----
  __shared__ uint32_t wzl[768 * 16];     // 48 KB, z-part of W_ih, XOR-swizzled
  __shared__ uint32_t encw[64 * 128];    // 32 KB, enc h-part, rotation-swizzled
  __shared__ __align__(16) f16 hf[2][256];
  __shared__ float encp[1024];
  __shared__ uint32_t zu[16];

  for (int idx = tid; idx < 768 * 16; idx += 1024) {
    int j = idx >> 4, pz = idx & 15;
    wzl[j * 16 + (pz ^ (j & 15))] = pkh2(W_ih[(size_t)j * 96 + 64 + 2 * pz],
                                         W_ih[(size_t)j * 96 + 64 + 2 * pz + 1]);
  }
  for (int idx = tid; idx < 64 * 128; idx += 1024) {
    int row = idx >> 7, pc = idx & 127;
    const float* src = (row < 32) ? (emW + (size_t)row * 320 + 64)
                                  : (esW + (size_t)(row - 32) * 320 + 64);
    encw[(row << 7) + ((pc + row) & 127)] = pkh2(src[2 * pc], src[2 * pc + 1]);
  }

  float hm = 0.0f;
  if (q == 0) {
    hm = first ? 0.0f : hws[b * 256 + hrow];
    hf[0][hrow] = (f16)hm;
  }
  __syncthreads();

  // ---- stream prefetch for t=0 ----
  float pf_g0 = 0.0f, pf_g1 = 0.0f, pf_g2 = 0.0f;
  if (q == 0) {
    const f16* gp0 = gix + (size_t)b * 768;
    pf_g0 = (float)gp0[hrow]; pf_g1 = (float)gp0[hrow + 256]; pf_g2 = (float)gp0[hrow + 512];
  }
  float pf_zm = 0.0f, pf_zl = 0.0f, pf_ep = 0.0f;
  if (tid < 32) {
    const f16* zp = zx + (size_t)b * 64;
    pf_zm = (float)zp[tid]; pf_zl = (float)zp[32 + tid];
    pf_ep = eps[((size_t)t0 * NB + b) * 32 + tid];
  }

  const int erow = tid & 63, eq = tid >> 6;      // enc partials: 16 groups x 8 k-pairs
  const uint32_t* encw_r = encw + (erow << 7);
  const int zswz = hrow & 15;

  for (int tl = 0; tl < Tlen; ++tl) {
    const int cur = tl & 1, nxt = cur ^ 1;
    const uint32_t* hu = (const uint32_t*)&hf[cur][0];

    // ---- phase A: encoder h-part partials (8 k-pairs per thread) ----
    float epacc = 0.0f;
    #pragma unroll
    for (int p = 0; p < 8; ++p) {
      int pc = eq * 8 + p;
      epacc = dot2u(encw_r[(pc + erow) & 127], hu[pc], epacc);
    }
    encp[tid] = epacc;
    __syncthreads();  // b1

    // ---- phase B: z (32 threads) || gh (all threads) ----
    if (tid < 32) {
      float mu = pf_zm, lv = pf_zl;
      #pragma unroll
      for (int qq = 0; qq < 16; ++qq) {
        mu += encp[qq * 64 + tid];
        lv += encp[qq * 64 + 32 + tid];
      }
      float z = mu + pf_ep * exp2f(0.72134752f * lv);   // mu + eps*exp(0.5*lv)
      ((f16*)zu)[tid] = (f16)z;
    }
    // gh: 8 x ds_read_b128 (bank-disjoint across quarters) + 96 dot2
    const uint4* hu4 = (const uint4*)hu;
    float g0 = 0.0f, g1 = 0.0f, g2 = 0.0f;
    #pragma unroll
    for (int p4 = 0; p4 < 8; ++p4) {
      uint4 u4 = hu4[q + 4 * p4];
      g0 = dot2u(wh[0][4 * p4],     u4.x, g0);
      g1 = dot2u(wh[1][4 * p4],     u4.x, g1);
      g2 = dot2u(wh[2][4 * p4],     u4.x, g2);
      g0 = dot2u(wh[0][4 * p4 + 1], u4.y, g0);
      g1 = dot2u(wh[1][4 * p4 + 1], u4.y, g1);
      g2 = dot2u(wh[2][4 * p4 + 1], u4.y, g2);
      g0 = dot2u(wh[0][4 * p4 + 2], u4.z, g0);
      g1 = dot2u(wh[1][4 * p4 + 2], u4.z, g1);
      g2 = dot2u(wh[2][4 * p4 + 2], u4.z, g2);
      g0 = dot2u(wh[0][4 * p4 + 3], u4.w, g0);
      g1 = dot2u(wh[1][4 * p4 + 3], u4.w, g1);
      g2 = dot2u(wh[2][4 * p4 + 3], u4.w, g2);
    }
    __syncthreads();  // b2  (z visible)

    // ---- phase C: gi_z (4 packed k per quarter), 4-lane reduce, gates ----
    float q0 = 0.0f, q1 = 0.0f, q2 = 0.0f;
    #pragma unroll
    for (int p = 0; p < 4; ++p) {
      int pz = q * 4 + p;
      int swz = pz ^ zswz;
      uint32_t u = zu[pz];
      q0 = dot2u(wzl[(hrow)       * 16 + swz], u, q0);
      q1 = dot2u(wzl[(hrow + 256) * 16 + swz], u, q1);
      q2 = dot2u(wzl[(hrow + 512) * 16 + swz], u, q2);
    }
    // r,u gates: fold z-part in (sigmoid of total sum). n gate: keep the
    // z-part separate (it must NOT be scaled by r).
    g0 += q0; g1 += q1; g2 += q2;
    g0 += __shfl_xor(g0, 1); g0 += __shfl_xor(g0, 2);
    g1 += __shfl_xor(g1, 1); g1 += __shfl_xor(g1, 2);
    g2 += __shfl_xor(g2, 1); g2 += __shfl_xor(g2, 2);
    float z_n = q2 + __shfl_xor(q2, 1);
    z_n += __shfl_xor(z_n, 2);       // full z-part of n row
    float n_h = g2 - z_n;            // pure W_hh_n @ h

    if (q == 0) {
      float r  = sigm(pf_g0 + g0);
      float uu = sigm(pf_g1 + g1);
      float n  = tanh_f(pf_g2 + z_n + r * (n_h + bhn));
      hm = (1.0f - uu) * n + uu * hm;
      hf[nxt][hrow] = (f16)hm;
    }

    // ---- prefetch streams for tl+1 ----
    int tn = (tl + 1 < Tlen) ? tl + 1 : tl;
    if (q == 0) {
      const f16* gp = gix + ((size_t)tn * NB + b) * 768;
      pf_g0 = (float)gp[hrow]; pf_g1 = (float)gp[hrow + 256]; pf_g2 = (float)gp[hrow + 512];
    }
    if (tid < 32) {
      const f16* zp = zx + ((size_t)tn * NB + b) * 64;
      pf_zm = (float)zp[tid]; pf_zl = (float)zp[32 + tid];
      pf_ep = eps[((size_t)(t0 + tn) * NB + b) * 32 + tid];
    }
    __syncthreads();  // b3  (h_new visible, streams in flight)
  }

  if (q == 0) {
    if (last) out[b * 256 + hrow] = hm;
    else      hws[b * 256 + hrow] = hm;
  }
}

extern "C" void kernel_launch(void* const* d_in, const int* in_sizes, int n_in,
                              void* d_out, int out_size, void* d_ws, size_t ws_size,
                              hipStream_t stream) {
  const float* x    = (const float*)d_in[0];
  const float* eps  = (const float*)d_in[1];
  const float* emW  = (const float*)d_in[2];
  const float* emb  = (const float*)d_in[3];
  const float* esW  = (const float*)d_in[4];
  const float* esb  = (const float*)d_in[5];
  const float* W_ih = (const float*)d_in[10];
  const float* W_hh = (const float*)d_in[11];
  const float* b_ih = (const float*)d_in[12];
  const float* b_hh = (const float*)d_in[13];
  float* out = (float*)d_out;

  const size_t hbytes = (size_t)NB * 256 * 4;       // 256 KB h carry
  const size_t wbytes = (size_t)98304 * 4;          // 384 KB packed W_hh
  int Tc = TSEQ;
  while (Tc > 8 && hbytes + wbytes + (size_t)Tc * NB * (768 + 64) * 2 > ws_size) Tc >>= 1;

  float*    hws  = (float*)d_ws;
  uint32_t* whpk = (uint32_t*)((char*)d_ws + hbytes);
  f16*      gix  = (f16*)((char*)d_ws + hbytes + wbytes);
  f16*      zx   = gix + (size_t)Tc * NB * 768;

  vrnn_pack<<<dim3(24), dim3(1024), 0, stream>>>(W_hh, whpk);

  int nch = TSEQ / Tc;
  int TT  = Tc < 64 ? Tc : 64;
  int nTT = Tc / TT;

  for (int c = 0; c < nch; ++c) {
    vrnn_pre<<<dim3(NB * nTT), dim3(256), 0, stream>>>(
        x, W_ih, b_ih, b_hh, emW, emb, esW, esb, gix, zx, c * Tc, TT, nTT);
    vrnn_rec<<<dim3(NB), dim3(1024), 0, stream>>>(
        gix, zx, eps, whpk, W_ih, emW, esW, b_hh, hws, out,
        c * Tc, Tc, c == 0 ? 1 : 0, c == nch - 1 ? 1 : 0);
  }
}

// Round 12
// 4714.771 us; speedup vs baseline: 3.3515x; 2.9044x over previous
//
#include <hip/hip_runtime.h>
#include <stdint.h>

#define NB 256      // batch
#define TSEQ 1024   // sequence length
#define TT_MAX 64

// W_hh per-row split (128 f16-pairs per gate row)
#define REG_P 40            // pairs/row in registers (3*40 = 120 VGPRs)
#define LDS_P 36            // pairs/row in LDS (3*36 = 108 u32/thread)
#define STR_P 52            // pairs/row streamed from L2 每 step (3*13 uint4)
#define LDSTR 116           // u32 stride of per-thread LDS slice (16B-aligned, even bank spread)

typedef _Float16 f16;
typedef _Float16 h2 __attribute__((ext_vector_type(2)));

static __device__ __forceinline__ uint32_t pkh2(float a, float b) {
  h2 v; v[0] = (f16)a; v[1] = (f16)b;
  return __builtin_bit_cast(uint32_t, v);
}

#if __has_builtin(__builtin_amdgcn_fdot2)
static __device__ __forceinline__ float dot2u(uint32_t w, uint32_t h, float c) {
  return __builtin_amdgcn_fdot2(__builtin_bit_cast(h2, w), __builtin_bit_cast(h2, h), c, false);
}
#else
static __device__ __forceinline__ float dot2u(uint32_t w, uint32_t h, float c) {
  h2 a = __builtin_bit_cast(h2, w), b = __builtin_bit_cast(h2, h);
  return c + (float)a[0] * (float)b[0] + (float)a[1] * (float)b[1];
}
#endif

#if __has_builtin(__builtin_amdgcn_rcpf)
#define RCPF(x) __builtin_amdgcn_rcpf(x)
#else
#define RCPF(x) (1.0f / (x))
#endif

static __device__ __forceinline__ float sigm(float x) {
  return RCPF(1.0f + exp2f(-1.44269504f * x));
}
static __device__ __forceinline__ float tanh_f(float x) {
  return 1.0f - 2.0f * RCPF(1.0f + exp2f(2.88539008f * x));
}

// ---------------------------------------------------------------------------
// One-time weight pack (f16). Thread t owns gate rows (t, t+256, t+512).
//  whr: REG part,  [(rr*10 + p/4)*256 + t] uint4, pairs [0,40)
//  whl: LDS part,  [t*LDSTR + rr*36 + p],  pairs [40,76)
//  whs: STREAM part,[(rr*13 + p/4)*256 + t] uint4, pairs [76,128)
//  whz: W_ih z-cols,[(rr*4 + p/4)*256 + t] uint4, 16 pairs
// ---------------------------------------------------------------------------
__global__ __launch_bounds__(256) void vrnn_pack(
    const float* __restrict__ W_hh, const float* __restrict__ W_ih,
    uint32_t* __restrict__ whr, uint32_t* __restrict__ whl,
    uint32_t* __restrict__ whs, uint32_t* __restrict__ whz)
{
  const int t = threadIdx.x;
  for (int rr = 0; rr < 3; ++rr) {
    const float* R = W_hh + (size_t)(t + rr * 256) * 256;
    for (int p = 0; p < REG_P; ++p)
      whr[(((size_t)rr * 10 + (p >> 2)) * 256 + t) * 4 + (p & 3)] = pkh2(R[2 * p], R[2 * p + 1]);
    for (int p = 0; p < LDS_P; ++p)
      whl[(size_t)t * LDSTR + rr * LDS_P + p] = pkh2(R[2 * (p + REG_P)], R[2 * (p + REG_P) + 1]);
    for (int p = 0; p < STR_P; ++p)
      whs[(((size_t)rr * 13 + (p >> 2)) * 256 + t) * 4 + (p & 3)] =
          pkh2(R[2 * (p + REG_P + LDS_P)], R[2 * (p + REG_P + LDS_P) + 1]);
    const float* Z = W_ih + (size_t)(t + rr * 256) * 96 + 64;
    for (int p = 0; p < 16; ++p)
      whz[(((size_t)rr * 4 + (p >> 2)) * 256 + t) * 4 + (p & 3)] = pkh2(Z[2 * p], Z[2 * p + 1]);
  }
}

// ---------------------------------------------------------------------------
// Precompute kernel (unchanged): gi_x'[t][b][768], zx'[t][b][64]
// ---------------------------------------------------------------------------
__global__ __launch_bounds__(256, 2) void vrnn_pre(
    const float* __restrict__ x, const float* __restrict__ W_ih,
    const float* __restrict__ b_ih, const float* __restrict__ b_hh,
    const float* __restrict__ emW, const float* __restrict__ emb,
    const float* __restrict__ esW, const float* __restrict__ esb,
    f16* __restrict__ gix, f16* __restrict__ zx,
    int chunk_t0, int TT, int nTT)
{
  const int tid = threadIdx.x;
  const int b  = blockIdx.x / nTT;
  const int tt = blockIdx.x % nTT;
  const int tloc0 = tt * TT;

  uint32_t wx[3][32];
  float bias[3];
  #pragma unroll
  for (int rr = 0; rr < 3; ++rr) {
    int j = tid + rr * 256;
    const float4* wr = (const float4*)(W_ih + (size_t)j * 96);
    #pragma unroll
    for (int p4 = 0; p4 < 16; ++p4) {
      float4 v = wr[p4];
      wx[rr][2 * p4]     = pkh2(v.x, v.y);
      wx[rr][2 * p4 + 1] = pkh2(v.z, v.w);
    }
    bias[rr] = b_ih[j] + (rr < 2 ? b_hh[j] : 0.0f);  // fold b_hh into r,z rows only
  }
  uint32_t we[32]; float ebias = 0.0f;
  if (tid < 64) {
    const float* src = (tid < 32) ? (emW + (size_t)tid * 320)
                                  : (esW + (size_t)(tid - 32) * 320);
    #pragma unroll
    for (int p = 0; p < 32; ++p) we[p] = pkh2(src[2 * p], src[2 * p + 1]);
    ebias = (tid < 32) ? emb[tid] : esb[tid - 32];
  }

  __shared__ uint32_t xs[TT_MAX * 32];
  for (int idx = tid; idx < TT * 32; idx += 256) {
    int tl = idx >> 5, pk = idx & 31;
    size_t base = ((size_t)b * TSEQ + (chunk_t0 + tloc0 + tl)) * 64 + 2 * pk;
    xs[idx] = pkh2(x[base], x[base + 1]);
  }
  __syncthreads();

  for (int tl = 0; tl < TT; ++tl) {
    float a0 = bias[0], a1 = bias[1], a2 = bias[2];
    #pragma unroll
    for (int p = 0; p < 32; ++p) {
      uint32_t u = xs[tl * 32 + p];
      a0 = dot2u(wx[0][p], u, a0);
      a1 = dot2u(wx[1][p], u, a1);
      a2 = dot2u(wx[2][p], u, a2);
    }
    size_t ob = (size_t)(tloc0 + tl) * NB + b;
    f16* g = gix + ob * 768;
    g[tid] = (f16)a0; g[tid + 256] = (f16)a1; g[tid + 512] = (f16)a2;
    if (tid < 64) {
      float a3 = ebias;
      #pragma unroll
      for (int p = 0; p < 32; ++p) a3 = dot2u(we[p], xs[tl * 32 + p], a3);
      zx[ob * 64 + tid] = (f16)a3;
    }
  }
}

// ---------------------------------------------------------------------------
// Recurrent kernel v5: 256 threads (4 waves), one block per batch element.
// R8-R11 lesson: hipcc budget = 1024/waves-in-block (2-blocks/CU heuristic,
// un-overridable) -> max resident regs/block = 256KB < W_hh's 384KB. So:
// per gate row, 40 pairs in regs (pinned), 36 in LDS (own slice, stride 116),
// 52 streamed from a SHARED L2-resident region each step. Thread t owns
// hidden unit t fully (no cross-lane reduction at all).
// ---------------------------------------------------------------------------
__global__ __launch_bounds__(256, 2) void vrnn_rec(
    const f16* __restrict__ gix, const f16* __restrict__ zx,
    const float* __restrict__ eps,
    const uint32_t* __restrict__ whr, const uint32_t* __restrict__ whl_g,
    const uint32_t* __restrict__ whs, const uint32_t* __restrict__ whz,
    const float* __restrict__ emW, const float* __restrict__ esW,
    const float* __restrict__ b_hh,
    float* __restrict__ hws, float* __restrict__ out,
    int t0, int Tlen, int first, int last)
{
  const int t = threadIdx.x;
  const int b = blockIdx.x;

  // ---- register weights (pinned vs rematerialization) ----
  uint32_t wrg[3][REG_P];          // 120 VGPRs
  {
    const uint4* whr4 = (const uint4*)whr;
    #pragma unroll
    for (int c = 0; c < 30; ++c) {
      uint4 v = whr4[c * 256 + t];
      int rr = c / 10, p4 = c % 10;
      wrg[rr][4 * p4]     = v.x; wrg[rr][4 * p4 + 1] = v.y;
      wrg[rr][4 * p4 + 2] = v.z; wrg[rr][4 * p4 + 3] = v.w;
    }
  }
  uint32_t wz[3][16];              // 48 VGPRs
  {
    const uint4* whz4 = (const uint4*)whz;
    #pragma unroll
    for (int c = 0; c < 12; ++c) {
      uint4 v = whz4[c * 256 + t];
      int rr = c / 4, p4 = c % 4;
      wz[rr][4 * p4]     = v.x; wz[rr][4 * p4 + 1] = v.y;
      wz[rr][4 * p4 + 2] = v.z; wz[rr][4 * p4 + 3] = v.w;
    }
  }
  #pragma unroll
  for (int rr = 0; rr < 3; ++rr) {
    #pragma unroll
    for (int i = 0; i < REG_P; ++i) asm volatile("" : "+v"(wrg[rr][i]));
    #pragma unroll
    for (int i = 0; i < 16; ++i)   asm volatile("" : "+v"(wz[rr][i]));
  }
  const float bhn = b_hh[512 + t];

  // ---- LDS: W_hh middle slices + enc weights + state (≈154 KB) ----
  __shared__ uint32_t lwh[256 * LDSTR];   // 118,784 B
  __shared__ uint32_t encw[64 * 128];     // 32,768 B, rotation-swizzled
  __shared__ __align__(16) f16 hf[2][256];
  __shared__ float encp[256];
  __shared__ uint32_t zu[16];

  {
    const uint4* src = (const uint4*)(whl_g + (size_t)t * LDSTR);
    uint4* dst = (uint4*)(lwh + (size_t)t * LDSTR);
    #pragma unroll
    for (int j = 0; j < LDSTR / 4; ++j) dst[j] = src[j];
  }
  for (int idx = t; idx < 64 * 128; idx += 256) {
    int row = idx >> 7, pc = idx & 127;
    const float* src = (row < 32) ? (emW + (size_t)row * 320 + 64)
                                  : (esW + (size_t)(row - 32) * 320 + 64);
    encw[(row << 7) + ((pc + row) & 127)] = pkh2(src[2 * pc], src[2 * pc + 1]);
  }

  float hm = first ? 0.0f : hws[b * 256 + t];
  hf[0][t] = (f16)hm;
  __syncthreads();

  // ---- stream prefetch for t=0 ----
  const f16* gp0 = gix + (size_t)b * 768;
  float pf_g0 = (float)gp0[t], pf_g1 = (float)gp0[t + 256], pf_g2 = (float)gp0[t + 512];
  float pf_zm = 0.0f, pf_zl = 0.0f, pf_ep = 0.0f;
  if (t < 32) {
    const f16* zp = zx + (size_t)b * 64;
    pf_zm = (float)zp[t]; pf_zl = (float)zp[32 + t];
    pf_ep = eps[((size_t)t0 * NB + b) * 32 + t];
  }

  const int e = t & 63, s = t >> 6;          // s is wave-uniform (wave id)
  const uint32_t* encw_r = encw + (e << 7);
  const uint32_t* myl = lwh + (size_t)t * LDSTR;
  const uint4* whs4 = (const uint4*)whs;

  for (int tl = 0; tl < Tlen; ++tl) {
    const int cur = tl & 1, nxt = cur ^ 1;
    const uint32_t* hu = (const uint32_t*)&hf[cur][0];
    const uint4* hu4 = (const uint4*)hu;

    // ---- phase A: encoder h-part partials (32 k-pairs per thread) ----
    float ep_ = 0.0f;
    #pragma unroll
    for (int p = 0; p < 32; ++p) {
      int pc = s * 32 + p;
      ep_ = dot2u(encw_r[(pc + e) & 127], hu[pc], ep_);
    }
    encp[t] = ep_;
    __syncthreads();  // b1

    // ---- phase B: z (32 threads) || gh (all threads, full K locally) ----
    if (t < 32) {
      float mu = pf_zm, lv = pf_zl;
      #pragma unroll
      for (int ss = 0; ss < 4; ++ss) {
        mu += encp[ss * 64 + t];
        lv += encp[ss * 64 + 32 + t];
      }
      float z = mu + pf_ep * exp2f(0.72134752f * lv);   // mu + eps*exp(0.5*lv)
      ((f16*)zu)[t] = (f16)z;
    }
    float g0 = 0.0f, g1 = 0.0f, g2 = 0.0f;
    // pairs [0,40): register weights
    #pragma unroll
    for (int g4 = 0; g4 < 10; ++g4) {
      uint4 u4 = hu4[g4];
      g0 = dot2u(wrg[0][4 * g4],     u4.x, g0);
      g1 = dot2u(wrg[1][4 * g4],     u4.x, g1);
      g2 = dot2u(wrg[2][4 * g4],     u4.x, g2);
      g0 = dot2u(wrg[0][4 * g4 + 1], u4.y, g0);
      g1 = dot2u(wrg[1][4 * g4 + 1], u4.y, g1);
      g2 = dot2u(wrg[2][4 * g4 + 1], u4.y, g2);
      g0 = dot2u(wrg[0][4 * g4 + 2], u4.z, g0);
      g1 = dot2u(wrg[1][4 * g4 + 2], u4.z, g1);
      g2 = dot2u(wrg[2][4 * g4 + 2], u4.z, g2);
      g0 = dot2u(wrg[0][4 * g4 + 3], u4.w, g0);
      g1 = dot2u(wrg[1][4 * g4 + 3], u4.w, g1);
      g2 = dot2u(wrg[2][4 * g4 + 3], u4.w, g2);
    }
    // pairs [40,76): LDS own slice
    #pragma unroll
    for (int g4 = 0; g4 < 9; ++g4) {
      uint4 u4 = hu4[10 + g4];
      uint4 w0 = *(const uint4*)(myl + 0 * LDS_P + 4 * g4);
      uint4 w1 = *(const uint4*)(myl + 1 * LDS_P + 4 * g4);
      uint4 w2 = *(const uint4*)(myl + 2 * LDS_P + 4 * g4);
      g0 = dot2u(w0.x, u4.x, g0); g1 = dot2u(w1.x, u4.x, g1); g2 = dot2u(w2.x, u4.x, g2);
      g0 = dot2u(w0.y, u4.y, g0); g1 = dot2u(w1.y, u4.y, g1); g2 = dot2u(w2.y, u4.y, g2);
      g0 = dot2u(w0.z, u4.z, g0); g1 = dot2u(w1.z, u4.z, g1); g2 = dot2u(w2.z, u4.z, g2);
      g0 = dot2u(w0.w, u4.w, g0); g1 = dot2u(w1.w, u4.w, g1); g2 = dot2u(w2.w, u4.w, g2);
    }
    // pairs [76,128): streamed from shared L2-resident region, per row
    #pragma unroll
    for (int rr = 0; rr < 3; ++rr) {
      uint4 sbuf[13];
      #pragma unroll
      for (int j = 0; j < 13; ++j) sbuf[j] = whs4[(rr * 13 + j) * 256 + t];
      float acc = 0.0f;
      #pragma unroll
      for (int j = 0; j < 13; ++j) {
        uint4 u4 = hu4[19 + j];
        acc = dot2u(sbuf[j].x, u4.x, acc);
        acc = dot2u(sbuf[j].y, u4.y, acc);
        acc = dot2u(sbuf[j].z, u4.z, acc);
        acc = dot2u(sbuf[j].w, u4.w, acc);
      }
      if      (rr == 0) g0 += acc;
      else if (rr == 1) g1 += acc;
      else              g2 += acc;
    }
    __syncthreads();  // b2  (zu visible)

    // ---- phase C: gi_z from broadcast z, gates (fully thread-local) ----
    float q0 = 0.0f, q1 = 0.0f, q2 = 0.0f;
    #pragma unroll
    for (int p = 0; p < 16; ++p) {
      uint32_t u = zu[p];          // broadcast read
      q0 = dot2u(wz[0][p], u, q0);
      q1 = dot2u(wz[1][p], u, q1);
      q2 = dot2u(wz[2][p], u, q2);
    }
    float r  = sigm(pf_g0 + g0 + q0);
    float uu = sigm(pf_g1 + g1 + q1);
    float n  = tanh_f(pf_g2 + q2 + r * (g2 + bhn));
    hm = (1.0f - uu) * n + uu * hm;
    hf[nxt][t] = (f16)hm;

    // ---- prefetch streams for tl+1 ----
    int tn = (tl + 1 < Tlen) ? tl + 1 : tl;
    const f16* gp = gix + ((size_t)tn * NB + b) * 768;
    pf_g0 = (float)gp[t]; pf_g1 = (float)gp[t + 256]; pf_g2 = (float)gp[t + 512];
    if (t < 32) {
      const f16* zp = zx + ((size_t)tn * NB + b) * 64;
      pf_zm = (float)zp[t]; pf_zl = (float)zp[32 + t];
      pf_ep = eps[((size_t)(t0 + tn) * NB + b) * 32 + t];
    }
    __syncthreads();  // b3  (h_new visible)
  }

  if (last) out[b * 256 + t] = hm;
  else      hws[b * 256 + t] = hm;
}

extern "C" void kernel_launch(void* const* d_in, const int* in_sizes, int n_in,
                              void* d_out, int out_size, void* d_ws, size_t ws_size,
                              hipStream_t stream) {
  const float* x    = (const float*)d_in[0];
  const float* eps  = (const float*)d_in[1];
  const float* emW  = (const float*)d_in[2];
  const float* emb  = (const float*)d_in[3];
  const float* esW  = (const float*)d_in[4];
  const float* esb  = (const float*)d_in[5];
  const float* W_ih = (const float*)d_in[10];
  const float* W_hh = (const float*)d_in[11];
  const float* b_ih = (const float*)d_in[12];
  const float* b_hh = (const float*)d_in[13];
  float* out = (float*)d_out;

  // workspace layout (16B-aligned regions)
  const size_t o_hws = 0;                       // 256 KB
  const size_t o_whr = 262144;                  // 30*256*16 = 122,880
  const size_t o_whl = o_whr + 122880;          // 116*256*4 = 118,784
  const size_t o_whs = o_whl + 118784;          // 39*256*16 = 159,744
  const size_t o_whz = o_whs + 159744;          // 12*256*16 = 49,152
  const size_t o_gix = o_whz + 49152;           // = 712,704
  int Tc = TSEQ;
  while (Tc > 8 && o_gix + (size_t)Tc * NB * (768 + 64) * 2 > ws_size) Tc >>= 1;

  float*    hws   = (float*)d_ws;
  uint32_t* whr   = (uint32_t*)((char*)d_ws + o_whr);
  uint32_t* whl_g = (uint32_t*)((char*)d_ws + o_whl);
  uint32_t* whs   = (uint32_t*)((char*)d_ws + o_whs);
  uint32_t* whz   = (uint32_t*)((char*)d_ws + o_whz);
  f16*      gix   = (f16*)((char*)d_ws + o_gix);
  f16*      zx    = gix + (size_t)Tc * NB * 768;

  vrnn_pack<<<dim3(1), dim3(256), 0, stream>>>(W_hh, W_ih, whr, whl_g, whs, whz);

  int nch = TSEQ / Tc;
  int TT  = Tc < 64 ? Tc : 64;
  int nTT = Tc / TT;

  for (int c = 0; c < nch; ++c) {
    vrnn_pre<<<dim3(NB * nTT), dim3(256), 0, stream>>>(
        x, W_ih, b_ih, b_hh, emW, emb, esW, esb, gix, zx, c * Tc, TT, nTT);
    vrnn_rec<<<dim3(NB), dim3(256), 0, stream>>>(
        gix, zx, eps, whr, whl_g, whs, whz, emW, esW, b_hh, hws, out,
        c * Tc, Tc, c == 0 ? 1 : 0, c == nch - 1 ? 1 : 0);
  }
}